// Round 3
// baseline (579.716 us; speedup 1.0000x reference)
//
#include <hip/hip_runtime.h>

// GraphSAGE 2-layer, N=100000, E=1200000, D: 64 -> 64 -> 32, fp32.
// R2: replace fp32 scatter-atomics (85% of R1 time) with a counting-sort CSR
// build (reused by both layers) + fused gather-mean + dense transform.

#define D1 64
#define D2 32

// ---- CSR build ----------------------------------------------------------

__global__ __launch_bounds__(256)
void count_deg(const int* __restrict__ dst, int* __restrict__ degi, int E) {
    int i = blockIdx.x * 256 + threadIdx.x;
    if (i < E) atomicAdd(&degi[dst[i]], 1);
}

// per-block sums of degi
__global__ __launch_bounds__(256)
void block_sums(const int* __restrict__ degi, int* __restrict__ partial, int N) {
    __shared__ int s[256];
    int i = blockIdx.x * 256 + threadIdx.x;
    int t = threadIdx.x;
    s[t] = (i < N) ? degi[i] : 0;
    __syncthreads();
    for (int off = 128; off > 0; off >>= 1) {
        if (t < off) s[t] += s[t + off];
        __syncthreads();
    }
    if (t == 0) partial[blockIdx.x] = s[0];
}

// exclusive scan of partial[NB], NB <= 512, single block of 512
__global__ __launch_bounds__(512)
void scan_partials(int* __restrict__ partial, int NB) {
    __shared__ int s[512];
    int t = threadIdx.x;
    int v = (t < NB) ? partial[t] : 0;
    s[t] = v;
    __syncthreads();
    for (int off = 1; off < 512; off <<= 1) {
        int add = (t >= off) ? s[t - off] : 0;
        __syncthreads();
        s[t] += add;
        __syncthreads();
    }
    if (t < NB) partial[t] = s[t] - v;   // exclusive
}

// per-block exclusive scan + offset -> rowstart, cursor
__global__ __launch_bounds__(256)
void write_rowstart(const int* __restrict__ degi, const int* __restrict__ partial,
                    int* __restrict__ rowstart, int* __restrict__ cursor,
                    int N, int E) {
    __shared__ int s[256];
    int i = blockIdx.x * 256 + threadIdx.x;
    int t = threadIdx.x;
    int v = (i < N) ? degi[i] : 0;
    s[t] = v;
    __syncthreads();
    for (int off = 1; off < 256; off <<= 1) {
        int add = (t >= off) ? s[t - off] : 0;
        __syncthreads();
        s[t] += add;
        __syncthreads();
    }
    int excl = s[t] - v + partial[blockIdx.x];
    if (i < N) {
        rowstart[i] = excl;
        cursor[i]   = excl;
    }
    if (i == 0) rowstart[N] = E;
}

__global__ __launch_bounds__(256)
void bucket_fill(const int* __restrict__ src, const int* __restrict__ dst,
                 int* __restrict__ cursor, int* __restrict__ nbr, int E) {
    int i = blockIdx.x * 256 + threadIdx.x;
    if (i < E) {
        int d = dst[i];
        int p = atomicAdd(&cursor[d], 1);
        nbr[p] = src[i];
    }
}

// ---- fused layer: out = act((mean nbrs feat) @ Wl + b + feat @ Wr) ------
// Block = 256 threads = 4 waves = 4 nodes. Wave lane = feature index.

template <int DOUT, bool RELU>
__global__ __launch_bounds__(256)
void sage_fused(const float* __restrict__ feat,
                const int* __restrict__ rowstart,
                const int* __restrict__ nbr,
                const float* __restrict__ Wl,   // [64][DOUT]
                const float* __restrict__ Wr,   // [64][DOUT]
                const float* __restrict__ bias, // [DOUT]
                float* __restrict__ outp,
                int N) {
    __shared__ float sWl[D1 * DOUT];
    __shared__ float sWr[D1 * DOUT];
    __shared__ float sB[DOUT];
    __shared__ float sM[4][D1];
    __shared__ float sX[4][D1];

    for (int i = threadIdx.x; i < D1 * DOUT; i += 256) {
        sWl[i] = Wl[i];
        sWr[i] = Wr[i];
    }
    if (threadIdx.x < DOUT) sB[threadIdx.x] = bias[threadIdx.x];

    int w = threadIdx.x >> 6;
    int lane = threadIdx.x & 63;
    int node = blockIdx.x * 4 + w;

    float mean = 0.0f, xv = 0.0f;
    if (node < N) {
        int r0 = rowstart[node];
        int r1 = rowstart[node + 1];
        float acc = 0.0f;
        for (int i = r0; i < r1; ++i) {
            int s = nbr[i];                       // broadcast load
            acc += feat[(size_t)s * D1 + lane];   // 256B coalesced row
        }
        mean = acc / fmaxf((float)(r1 - r0), 1.0f);
        xv = feat[(size_t)node * D1 + lane];
    }
    sM[w][lane] = mean;
    sX[w][lane] = xv;
    __syncthreads();

    if (node >= N) return;

    if (DOUT == 64) {
        int j = lane;
        float acc = sB[j];
        #pragma unroll
        for (int k = 0; k < D1; ++k) {
            acc = fmaf(sM[w][k], sWl[k * DOUT + j], acc);
            acc = fmaf(sX[w][k], sWr[k * DOUT + j], acc);
        }
        if (RELU) acc = fmaxf(acc, 0.0f);
        outp[(size_t)node * DOUT + j] = acc;
    } else {
        // DOUT==32: all 64 lanes busy — halves split the k-range, shfl-combine
        int j    = lane & (DOUT - 1);
        int half = lane >> 5;
        float acc = 0.0f;
        #pragma unroll
        for (int kk = 0; kk < 32; ++kk) {
            int k = half * 32 + kk;
            acc = fmaf(sM[w][k], sWl[k * DOUT + j], acc);
            acc = fmaf(sX[w][k], sWr[k * DOUT + j], acc);
        }
        acc += __shfl_xor(acc, 32, 64);
        if (half == 0) {
            float r = acc + sB[j];
            if (RELU) r = fmaxf(r, 0.0f);
            outp[(size_t)node * DOUT + j] = r;
        }
    }
}

// ---- launch -------------------------------------------------------------

extern "C" void kernel_launch(void* const* d_in, const int* in_sizes, int n_in,
                              void* d_out, int out_size, void* d_ws, size_t ws_size,
                              hipStream_t stream) {
    const float* x   = (const float*)d_in[0];
    const int*   ei  = (const int*)d_in[1];
    const float* W1l = (const float*)d_in[2];
    const float* W1r = (const float*)d_in[3];
    const float* b1  = (const float*)d_in[4];
    const float* W2l = (const float*)d_in[5];
    const float* W2r = (const float*)d_in[6];
    const float* b2  = (const float*)d_in[7];
    float* out = (float*)d_out;

    int N = in_sizes[0] / D1;
    int E = in_sizes[1] / 2;
    const int* src = ei;
    const int* dst = ei + E;

    // workspace layout (all 256B-aligned)
    char* ws = (char*)d_ws;
    auto alignup = [](size_t v) { return (v + 255) & ~(size_t)255; };
    size_t off = 0;
    int* degi     = (int*)(ws + off); off += alignup((size_t)N * 4);
    int* partial  = (int*)(ws + off); off += alignup(512 * 4);
    int* rowstart = (int*)(ws + off); off += alignup((size_t)(N + 1) * 4);
    int* cursor   = (int*)(ws + off); off += alignup((size_t)N * 4);
    int* nbr      = (int*)(ws + off); off += alignup((size_t)E * 4);
    float* h      = (float*)(ws + off);

    int NB = (N + 255) / 256;     // 391 <= 512

    hipMemsetAsync(degi, 0, (size_t)N * 4, stream);

    int eb = (E + 255) / 256;
    count_deg<<<eb, 256, 0, stream>>>(dst, degi, E);
    block_sums<<<NB, 256, 0, stream>>>(degi, partial, N);
    scan_partials<<<1, 512, 0, stream>>>(partial, NB);
    write_rowstart<<<NB, 256, 0, stream>>>(degi, partial, rowstart, cursor, N, E);
    bucket_fill<<<eb, 256, 0, stream>>>(src, dst, cursor, nbr, E);

    int nb4 = (N + 3) / 4;
    sage_fused<64, true ><<<nb4, 256, 0, stream>>>(x, rowstart, nbr, W1l, W1r, b1, h, N);
    sage_fused<32, false><<<nb4, 256, 0, stream>>>(h, rowstart, nbr, W2l, W2r, b2, out, N);
}

// Round 4
// 336.995 us; speedup vs baseline: 1.7203x; 1.7203x over previous
//
#include <hip/hip_runtime.h>

// GraphSAGE 2-layer, N=100000, E=1200000, D: 64 -> 64 -> 32, fp32.
// R4: split gather (latency-bound, no-LDS, unrolled MLP) from dense transform
// (VALU-bound skinny GEMM: lane=node, 64 VGPR accumulators, scalar weight
// streaming, per-wave LDS transpose tiles, zero barriers).

#define D1 64

// ---- CSR build ----------------------------------------------------------

__global__ __launch_bounds__(256)
void count_deg(const int* __restrict__ dst, int* __restrict__ degi, int E) {
    int i = blockIdx.x * 256 + threadIdx.x;
    if (i < E) atomicAdd(&degi[dst[i]], 1);
}

__global__ __launch_bounds__(256)
void block_sums(const int* __restrict__ degi, int* __restrict__ partial, int N) {
    __shared__ int s[256];
    int i = blockIdx.x * 256 + threadIdx.x;
    int t = threadIdx.x;
    s[t] = (i < N) ? degi[i] : 0;
    __syncthreads();
    for (int off = 128; off > 0; off >>= 1) {
        if (t < off) s[t] += s[t + off];
        __syncthreads();
    }
    if (t == 0) partial[blockIdx.x] = s[0];
}

__global__ __launch_bounds__(512)
void scan_partials(int* __restrict__ partial, int NB) {
    __shared__ int s[512];
    int t = threadIdx.x;
    int v = (t < NB) ? partial[t] : 0;
    s[t] = v;
    __syncthreads();
    for (int off = 1; off < 512; off <<= 1) {
        int add = (t >= off) ? s[t - off] : 0;
        __syncthreads();
        s[t] += add;
        __syncthreads();
    }
    if (t < NB) partial[t] = s[t] - v;   // exclusive
}

__global__ __launch_bounds__(256)
void write_rowstart(const int* __restrict__ degi, const int* __restrict__ partial,
                    int* __restrict__ rowstart, int* __restrict__ cursor,
                    int N, int E) {
    __shared__ int s[256];
    int i = blockIdx.x * 256 + threadIdx.x;
    int t = threadIdx.x;
    int v = (i < N) ? degi[i] : 0;
    s[t] = v;
    __syncthreads();
    for (int off = 1; off < 256; off <<= 1) {
        int add = (t >= off) ? s[t - off] : 0;
        __syncthreads();
        s[t] += add;
        __syncthreads();
    }
    int excl = s[t] - v + partial[blockIdx.x];
    if (i < N) {
        rowstart[i] = excl;
        cursor[i]   = excl;
    }
    if (i == 0) rowstart[N] = E;
}

__global__ __launch_bounds__(256)
void bucket_fill(const int* __restrict__ src, const int* __restrict__ dst,
                 int* __restrict__ cursor, int* __restrict__ nbr, int E) {
    int i = blockIdx.x * 256 + threadIdx.x;
    if (i < E) {
        int d = dst[i];
        int p = atomicAdd(&cursor[d], 1);
        nbr[p] = src[i];
    }
}

// ---- gather: mean of neighbor rows. Wave per node, lane = feature. ------
// No LDS -> max occupancy. Unroll 4 -> 4 independent row loads in flight.

__global__ __launch_bounds__(256)
void gather_mean(const float* __restrict__ feat,
                 const int* __restrict__ rowstart,
                 const int* __restrict__ nbr,
                 float* __restrict__ mean, int N) {
    int wid  = (blockIdx.x * 256 + threadIdx.x) >> 6;
    int lane = threadIdx.x & 63;
    if (wid >= N) return;
    int r0 = rowstart[wid];
    int r1 = rowstart[wid + 1];
    float acc = 0.0f;
    int i = r0;
    for (; i + 4 <= r1; i += 4) {
        int s0 = nbr[i + 0];
        int s1 = nbr[i + 1];
        int s2 = nbr[i + 2];
        int s3 = nbr[i + 3];
        float v0 = feat[(size_t)s0 * D1 + lane];
        float v1 = feat[(size_t)s1 * D1 + lane];
        float v2 = feat[(size_t)s2 * D1 + lane];
        float v3 = feat[(size_t)s3 * D1 + lane];
        acc += (v0 + v1) + (v2 + v3);
    }
    for (; i < r1; ++i) {
        acc += feat[(size_t)nbr[i] * D1 + lane];
    }
    float inv = 1.0f / fmaxf((float)(r1 - r0), 1.0f);
    mean[(size_t)wid * D1 + lane] = acc * inv;
}

// ---- dense: out[n][j] = act(sum_k mean[n][k] Wm[k][j] + x[n][k] Wx[k][j] + b[j])
// Block = 256 = 4 waves; wave owns 64 nodes (lane = node).
// A staged+transposed in a PRIVATE per-wave LDS tile (no barriers).
// Weights streamed via wave-uniform loads -> s_load + v_fmac (SGPR operand).

template <int DOUT, bool RELU>
__global__ __launch_bounds__(256)
void dense_sage(const float* __restrict__ Am,    // mean [N][64]
                const float* __restrict__ Ax,    // x or h [N][64]
                const float* __restrict__ Wm,    // [64][DOUT]
                const float* __restrict__ Wx,    // [64][DOUT]
                const float* __restrict__ bias,  // [DOUT]
                float* __restrict__ outp, int N) {
    __shared__ float tile[4][32 * 65];
    int w    = threadIdx.x >> 6;
    int lane = threadIdx.x & 63;
    float* tl = tile[w];
    int n0 = blockIdx.x * 256 + w * 64;

    float c[DOUT];
    #pragma unroll
    for (int j = 0; j < DOUT; ++j) c[j] = bias[j];

    #pragma unroll
    for (int chunk = 0; chunk < 4; ++chunk) {
        const float* A = (chunk < 2) ? Am : Ax;
        const float* W = (chunk < 2) ? Wm : Wx;
        int kc = (chunk & 1) * 32;

        // stage 64 rows x 32 cols of A, transposed: tl[k_local][node]
        #pragma unroll
        for (int t = 0; t < 8; ++t) {
            int n  = t * 8 + (lane >> 3);
            int c4 = (lane & 7) * 4;
            int row = n0 + n;
            float4 v = make_float4(0.f, 0.f, 0.f, 0.f);
            if (row < N) v = *(const float4*)&A[(size_t)row * D1 + kc + c4];
            tl[(c4 + 0) * 65 + n] = v.x;
            tl[(c4 + 1) * 65 + n] = v.y;
            tl[(c4 + 2) * 65 + n] = v.z;
            tl[(c4 + 3) * 65 + n] = v.w;
        }
        // same-wave write->read: compiler inserts lgkmcnt, no barrier needed

        const float* Wb = W + kc * DOUT;
        #pragma unroll 4
        for (int kl = 0; kl < 32; ++kl) {
            float a = tl[kl * 65 + lane];
            #pragma unroll
            for (int j = 0; j < DOUT; ++j) {
                c[j] = fmaf(a, Wb[kl * DOUT + j], c[j]);   // Wb idx wave-uniform
            }
        }
    }

    if (RELU) {
        #pragma unroll
        for (int j = 0; j < DOUT; ++j) c[j] = fmaxf(c[j], 0.0f);
    }

    // epilogue: lane holds the full output row -> LDS transpose -> float4 store
    #pragma unroll
    for (int jh = 0; jh < DOUT / 32; ++jh) {
        #pragma unroll
        for (int jj = 0; jj < 32; ++jj) {
            tl[jj * 65 + lane] = c[jh * 32 + jj];
        }
        #pragma unroll
        for (int t = 0; t < 8; ++t) {
            int f  = t * 64 + lane;     // float4 index in 64x32 half-tile
            int n  = f >> 3;            // row 0..63
            int c4 = (f & 7) * 4;       // col 0..28
            int row = n0 + n;
            if (row < N) {
                float4 v;
                v.x = tl[(c4 + 0) * 65 + n];
                v.y = tl[(c4 + 1) * 65 + n];
                v.z = tl[(c4 + 2) * 65 + n];
                v.w = tl[(c4 + 3) * 65 + n];
                *(float4*)&outp[(size_t)row * DOUT + jh * 32 + c4] = v;
            }
        }
    }
}

// ---- launch -------------------------------------------------------------

extern "C" void kernel_launch(void* const* d_in, const int* in_sizes, int n_in,
                              void* d_out, int out_size, void* d_ws, size_t ws_size,
                              hipStream_t stream) {
    const float* x   = (const float*)d_in[0];
    const int*   ei  = (const int*)d_in[1];
    const float* W1l = (const float*)d_in[2];
    const float* W1r = (const float*)d_in[3];
    const float* b1  = (const float*)d_in[4];
    const float* W2l = (const float*)d_in[5];
    const float* W2r = (const float*)d_in[6];
    const float* b2  = (const float*)d_in[7];
    float* out = (float*)d_out;

    int N = in_sizes[0] / D1;
    int E = in_sizes[1] / 2;
    const int* src = ei;
    const int* dst = ei + E;

    char* ws = (char*)d_ws;
    auto alignup = [](size_t v) { return (v + 255) & ~(size_t)255; };
    size_t off = 0;
    int*   rowstart = (int*)(ws + off); off += alignup((size_t)(N + 1) * 4);
    int*   cursor   = (int*)(ws + off); off += alignup((size_t)N * 4);
    int*   nbr      = (int*)(ws + off); off += alignup((size_t)E * 4);
    float* mean     = (float*)(ws + off); off += alignup((size_t)N * D1 * 4);
    float* h        = (float*)(ws + off);
    // degi/partial are dead before mean is first written -> alias into mean
    int* degi    = (int*)mean;
    int* partial = (int*)((char*)mean + alignup((size_t)N * 4));

    int NB = (N + 255) / 256;     // 391 <= 512
    int eb = (E + 255) / 256;

    hipMemsetAsync(degi, 0, (size_t)N * 4, stream);
    count_deg<<<eb, 256, 0, stream>>>(dst, degi, E);
    block_sums<<<NB, 256, 0, stream>>>(degi, partial, N);
    scan_partials<<<1, 512, 0, stream>>>(partial, NB);
    write_rowstart<<<NB, 256, 0, stream>>>(degi, partial, rowstart, cursor, N, E);
    bucket_fill<<<eb, 256, 0, stream>>>(src, dst, cursor, nbr, E);

    int gb = (N + 3) / 4;         // wave per node, 4 waves/block
    int db = (N + 255) / 256;     // 64 nodes per wave, 4 waves/block

    gather_mean<<<gb, 256, 0, stream>>>(x, rowstart, nbr, mean, N);
    dense_sage<64, true ><<<db, 256, 0, stream>>>(mean, x, W1l, W1r, b1, h, N);
    gather_mean<<<gb, 256, 0, stream>>>(h, rowstart, nbr, mean, N);
    dense_sage<32, false><<<db, 256, 0, stream>>>(mean, h, W2l, W2r, b2, out, N);
}